// Round 6
// baseline (272.905 us; speedup 1.0000x reference)
//
#include <hip/hip_runtime.h>

typedef unsigned short u16;
typedef unsigned int u32;
typedef float f32x4 __attribute__((ext_vector_type(4)));
typedef __bf16 bf16x8 __attribute__((ext_vector_type(8)));

#define S_LEN 2048
#define DMODEL 1024
#define NHEAD 16
#define DKH 64

__device__ __forceinline__ u16 f2bf(float f) {
    unsigned u = __float_as_uint(f);
    u += 0x7FFFu + ((u >> 16) & 1u);   // RNE
    return (u16)(u >> 16);
}

// packed f32x2 -> bf16x2 (RNE)
__device__ __forceinline__ u32 pkbf2(float a, float b) {
#if __has_builtin(__builtin_amdgcn_cvt_pk_bf16_f32)
    typedef __bf16 bf16x2_t __attribute__((ext_vector_type(2)));
    bf16x2_t r = __builtin_amdgcn_cvt_pk_bf16_f32(a, b);
    u32 u; __builtin_memcpy(&u, &r, 4); return u;
#else
    return (u32)f2bf(a) | ((u32)f2bf(b) << 16);
#endif
}

#if __has_builtin(__builtin_amdgcn_exp2f)
#define EXP2(x) __builtin_amdgcn_exp2f(x)
#else
#define EXP2(x) exp2f(x)
#endif

// wave-level LDS write->read ordering WITHOUT draining vmcnt (keeps glds prefetch alive)
__device__ __forceinline__ void lds_fence_wave() {
    __asm__ volatile("" ::: "memory");
    __builtin_amdgcn_s_waitcnt(0xC07F);   // lgkmcnt(0), vmcnt/expcnt untouched
    __asm__ volatile("" ::: "memory");
}

// async global->LDS, 16B per lane
__device__ __forceinline__ void glds16(const u16* g, u16* l) {
    __builtin_amdgcn_global_load_lds(
        (const __attribute__((address_space(1))) void*)(g),
        (__attribute__((address_space(3))) void*)(l), 16, 0, 0);
}

// ---------------- fused fp32 -> bf16 convert (x + 4 weights in one launch) ----------------
__global__ __launch_bounds__(256) void cvt_all(const float* __restrict__ x, const float* __restrict__ PQ,
                                               const float* __restrict__ PK, const float* __restrict__ PV,
                                               const float* __restrict__ PO,
                                               u16* __restrict__ xb, u16* __restrict__ Wqkv,
                                               u16* __restrict__ Wo) {
    int i = blockIdx.x * 256 + threadIdx.x;
    const float* src; u16* dst; int j;
    if (i < 2097152)      { src = x;  dst = xb;             j = i; }
    else if (i < 2359296) { src = PQ; dst = Wqkv;           j = i - 2097152; }
    else if (i < 2621440) { src = PK; dst = Wqkv + 1048576; j = i - 2359296; }
    else if (i < 2883584) { src = PV; dst = Wqkv + 2097152; j = i - 2621440; }
    else                  { src = PO; dst = Wo;             j = i - 2883584; }
    float4 v = reinterpret_cast<const float4*>(src)[j];
    uint2 o;
    o.x = pkbf2(v.x, v.y);
    o.y = pkbf2(v.z, v.w);
    reinterpret_cast<uint2*>(dst)[j] = o;
}

// ---------------- GEMM core: C = A * Bt^T, 128x128 tile, BK=32 ----------------
// 3-stage pipeline, prefetch distance 2, raw s_barrier + fine-grained vmcnt (never drain
// the in-flight stage). Conflict-free swizzle swiz(row)=(row>>1)&3.
// As/Bs each hold 3 buffers of 128x32 (24 KB each, 48 KB total).
__device__ __forceinline__ void gemm_core(const u16* __restrict__ A, const u16* __restrict__ Bt,
                                          int K, int m0, int n0,
                                          u16* As, u16* Bs, f32x4 acc[4][4]) {
    const int tid  = threadIdx.x;
    const int lane = tid & 63;
    const int quad = lane >> 4, l15 = lane & 15;
    const int w    = tid >> 6;
    const int mq   = w & 1, nq = w >> 1;

    // staging: LDS slot (row=c>>2, chunk=c&3) holds global chunk (c&3)^((row>>1)&3)
    const int c0 = tid, c1 = tid + 256;
    const int r0 = c0 >> 2, k0 = ((c0 & 3) ^ ((r0 >> 1) & 3)) * 8;
    const int r1 = c1 >> 2, k1 = ((c1 & 3) ^ ((r1 >> 1) & 3)) * 8;
    const u16* ga0 = A  + (size_t)(m0 + r0) * K + k0;
    const u16* ga1 = A  + (size_t)(m0 + r1) * K + k1;
    const u16* gb0 = Bt + (size_t)(n0 + r0) * K + k0;
    const u16* gb1 = Bt + (size_t)(n0 + r1) * K + k1;

    // reader: frag row = base16 + l15 -> chunk = quad ^ ((l15>>1)&3)  (lane-constant)
    // bank base = 16*(l15&1) + 4*(quad^((l15>>1)&3)) -> 8 groups x 2 lanes = 2-way (free)
    const int swz = (quad ^ ((l15 >> 1) & 3)) * 8;

    auto stage = [&](int buf, int kk) {
        u16* ad = As + buf * 4096;
        u16* bd = Bs + buf * 4096;
        glds16(ga0 + kk, ad + c0 * 8);
        glds16(ga1 + kk, ad + c1 * 8);
        glds16(gb0 + kk, bd + c0 * 8);
        glds16(gb1 + kk, bd + c1 * 8);
    };

    stage(0, 0);
    stage(1, 32);
    int cur = 0;
    for (int kk = 0; kk < K; kk += 32) {
        // wait for the oldest stage (tile kk) to land; the distance-1 stage stays in flight.
        // Last iteration has only its own stage outstanding -> must use vmcnt(0).
        __asm__ volatile("" ::: "memory");
        if (kk + 32 < K) __builtin_amdgcn_s_waitcnt(0x0F74);  // vmcnt(4), lgkm/exp untouched
        else             __builtin_amdgcn_s_waitcnt(0x0F70);  // vmcnt(0)
        __builtin_amdgcn_s_barrier();   // raw: no compiler-inserted vmcnt(0) drain
        __asm__ volatile("" ::: "memory");

        if (kk + 64 < K) {
            int nb = cur + 2; if (nb >= 3) nb -= 3;
            stage(nb, kk + 64);          // flies over this iter's and next iter's compute
        }
        const u16* ra = As + cur * 4096 + (mq * 64 + l15) * 32 + swz;
        const u16* rb = Bs + cur * 4096 + (nq * 64 + l15) * 32 + swz;
        bf16x8 af[4], bfv[4];
#pragma unroll
        for (int t = 0; t < 4; ++t) {
            af[t]  = *reinterpret_cast<const bf16x8*>(ra + t * 512);
            bfv[t] = *reinterpret_cast<const bf16x8*>(rb + t * 512);
        }
#pragma unroll
        for (int mt = 0; mt < 4; ++mt)
#pragma unroll
            for (int nt = 0; nt < 4; ++nt)
                acc[mt][nt] = __builtin_amdgcn_mfma_f32_16x16x32_bf16(af[mt], bfv[nt], acc[mt][nt], 0, 0, 0);
        ++cur; if (cur == 3) cur = 0;
    }
}

// ---------------- QKV projection + RoPE epilogue (Q pre-scaled by 1/8*log2e) ----------------
__global__ __launch_bounds__(256) void gemm_qkv_kernel(const u16* __restrict__ xb, const u16* __restrict__ Wqkv,
                                                       u16* __restrict__ Qb, u16* __restrict__ Kb,
                                                       u16* __restrict__ Vt) {
    __shared__ u16 As[3 * 128 * 32];
    __shared__ u16 Bs[3 * 128 * 32];
    f32x4 acc[4][4];
    const f32x4 zz = {0.f, 0.f, 0.f, 0.f};
#pragma unroll
    for (int i = 0; i < 4; ++i)
#pragma unroll
        for (int j = 0; j < 4; ++j) acc[i][j] = zz;

    const int m0 = blockIdx.y * 128;
    const int n0 = blockIdx.x * 128;
    gemm_core(xb, Wqkv, DMODEL, m0, n0, As, Bs, acc);

    const int lane = threadIdx.x & 63;
    const int quad = lane >> 4, l15 = lane & 15;
    const int w = threadIdx.x >> 6, mq = w & 1, nq = w >> 1;

#pragma unroll
    for (int nt = 0; nt < 4; ++nt) {
        const int ncol = n0 + nq*64 + nt*16 + l15;
        const int sel  = ncol >> 10;         // 0=Q,1=K,2=V (block-uniform)
        const int e    = ncol & 1023;
        const int h    = e >> 6, dk = e & 63;
#pragma unroll
        for (int mt = 0; mt < 4; ++mt) {
            const int mrow = m0 + mq*64 + mt*16 + quad*4;
            if (sel == 2) {
                int b = mrow >> 11, s = mrow & 2047;
                uint2 pv;
                pv.x = pkbf2(acc[mt][nt][0], acc[mt][nt][1]);
                pv.y = pkbf2(acc[mt][nt][2], acc[mt][nt][3]);
                *reinterpret_cast<uint2*>(&Vt[((size_t)(b * NHEAD + h) * DKH + dk) * S_LEN + s]) = pv;
            } else {
                float invf_rev = 0.15915494f * EXP2(-13.2877124f * (float)(dk & 62) * (1.0f / 64.0f));
                const float sc = sel ? 1.0f : 0.18033688f;   // fold softmax scale*log2e into Q
                u16* dst = sel ? Kb : Qb;
#pragma unroll
                for (int r = 0; r < 4; ++r) {
                    float val  = acc[mt][nt][r];
                    float part = __shfl_xor(val, 1);
                    int m = mrow + r;
                    int b = m >> 11, s = m & 2047;
                    float rev = (float)s * invf_rev;
                    float fr  = rev - floorf(rev);
#if __has_builtin(__builtin_amdgcn_sinf) && __has_builtin(__builtin_amdgcn_cosf)
                    float sn = __builtin_amdgcn_sinf(fr);   // sin(2*pi*fr)
                    float cs = __builtin_amdgcn_cosf(fr);
#else
                    float sn, cs;
                    __sincosf(fr * 6.2831853f, &sn, &cs);
#endif
                    sn *= sc; cs *= sc;
                    float o = (dk & 1) ? (part * sn + val * cs)
                                       : (val * cs - part * sn);
                    dst[((size_t)(b * NHEAD + h) * S_LEN + s) * DKH + dk] = f2bf(o);
                }
            }
        }
    }
}

// ---------------- flash attention: fixed-zero-max softmax, MFMA row-sums ----------------
__global__ __launch_bounds__(256) void attn_kernel(const u16* __restrict__ Qb, const u16* __restrict__ Kb,
                                                   const u16* __restrict__ Vt, u16* __restrict__ A2) {
    __shared__ u16 Ks[2][64 * 64];
    __shared__ u16 Vs[2][64 * 64];
    __shared__ u16 Ps[4][32 * 64];

    const int tid  = threadIdx.x;
    const int lane = tid & 63, w = tid >> 6;
    const int quad = lane >> 4, l15 = lane & 15;
    const int bh   = blockIdx.x & 63;
    const int qb   = 15 - (blockIdx.x >> 6);   // longest first
    const int b = bh >> 4, h = bh & 15;
    const int q0w = qb * 128 + w * 32;
    const int nkt = 2 * (qb + 1);
    const int sw7 = l15 & 7;
    const f32x4 zz = {0.f, 0.f, 0.f, 0.f};

    uint4 ob; ob.x = ob.y = ob.z = ob.w = 0x3F803F80u;
    bf16x8 ones; __builtin_memcpy(&ones, &ob, 16);

    bf16x8 qf[2][2];
#pragma unroll
    for (int qt2 = 0; qt2 < 2; ++qt2)
#pragma unroll
        for (int hh = 0; hh < 2; ++hh)
            qf[qt2][hh] = *reinterpret_cast<const bf16x8*>(
                Qb + ((size_t)bh * S_LEN + q0w + qt2 * 16 + l15) * DKH + hh * 32 + quad * 8);

    f32x4 ot[4][2], lacc[2];
#pragma unroll
    for (int mt = 0; mt < 4; ++mt) { ot[mt][0] = zz; ot[mt][1] = zz; }
    lacc[0] = zz; lacc[1] = zz;

    const int c0 = tid, c1 = tid + 256;
    const int r0 = c0 >> 3, kc0 = ((c0 & 7) ^ (r0 & 7)) * 8;
    const int r1 = c1 >> 3, kc1 = ((c1 & 7) ^ (r1 & 7)) * 8;
    const u16* gk0 = Kb + ((size_t)bh * S_LEN + r0) * DKH + kc0;
    const u16* gk1 = Kb + ((size_t)bh * S_LEN + r1) * DKH + kc1;
    const u16* gv0 = Vt + ((size_t)bh * DKH + r0) * S_LEN + kc0;
    const u16* gv1 = Vt + ((size_t)bh * DKH + r1) * S_LEN + kc1;
    u16* Pw = &Ps[w][0];
    u16* prow0 = Pw + l15 * 64 + (quad & 1) * 4;
    u16* prow1 = Pw + (16 + l15) * 64 + (quad & 1) * 4;

    auto stage = [&](u16* kdst, u16* vdst, int kt) {
        const size_t key0 = (size_t)kt * 64;
        glds16(gk0 + key0 * DKH, kdst + c0 * 8);
        glds16(gk1 + key0 * DKH, kdst + c1 * 8);
        glds16(gv0 + key0,       vdst + c0 * 8);
        glds16(gv1 + key0,       vdst + c1 * 8);
    };

    auto compute = [&](const u16* Kbuf, const u16* Vbuf, int key0) {
        f32x4 st[4][2];
#pragma unroll
        for (int kt4 = 0; kt4 < 4; ++kt4) {
            const u16* krow = Kbuf + (kt4 * 16 + l15) * 64;
            bf16x8 ka0 = *reinterpret_cast<const bf16x8*>(krow + (quad ^ sw7) * 8);
            bf16x8 ka1 = *reinterpret_cast<const bf16x8*>(krow + ((4 + quad) ^ sw7) * 8);
#pragma unroll
            for (int qt2 = 0; qt2 < 2; ++qt2) {
                f32x4 s = __builtin_amdgcn_mfma_f32_16x16x32_bf16(ka0, qf[qt2][0], zz, 0, 0, 0);
                st[kt4][qt2] = __builtin_amdgcn_mfma_f32_16x16x32_bf16(ka1, qf[qt2][1], s, 0, 0, 0);
            }
        }
        if (key0 + 63 > q0w) {
#pragma unroll
            for (int qt2 = 0; qt2 < 2; ++qt2) {
                const int qrow = q0w + qt2 * 16 + l15;
#pragma unroll
                for (int kt4 = 0; kt4 < 4; ++kt4) {
                    const int kbase = key0 + kt4 * 16 + quad * 4;
#pragma unroll
                    for (int r = 0; r < 4; ++r)
                        if (kbase + r > qrow) st[kt4][qt2][r] = -3.0e38f;
                }
            }
        }
#pragma unroll
        for (int qt2 = 0; qt2 < 2; ++qt2) {
            u16* prow = qt2 ? prow1 : prow0;
#pragma unroll
            for (int kt4 = 0; kt4 < 4; ++kt4) {
                uint2 pv;
                pv.x = pkbf2(EXP2(st[kt4][qt2][0]), EXP2(st[kt4][qt2][1]));
                pv.y = pkbf2(EXP2(st[kt4][qt2][2]), EXP2(st[kt4][qt2][3]));
                *reinterpret_cast<uint2*>(prow + ((2 * kt4 + (quad >> 1)) ^ sw7) * 8) = pv;
            }
        }
        lds_fence_wave();
        bf16x8 pb[2][2];
#pragma unroll
        for (int qt2 = 0; qt2 < 2; ++qt2)
#pragma unroll
            for (int kh = 0; kh < 2; ++kh)
                pb[qt2][kh] = *reinterpret_cast<const bf16x8*>(
                    Pw + (qt2 * 16 + l15) * 64 + ((kh * 4 + quad) ^ sw7) * 8);
#pragma unroll
        for (int mt = 0; mt < 4; ++mt) {
            const u16* vrow = Vbuf + (mt * 16 + l15) * 64;
            bf16x8 va0 = *reinterpret_cast<const bf16x8*>(vrow + (quad ^ sw7) * 8);
            bf16x8 va1 = *reinterpret_cast<const bf16x8*>(vrow + ((4 + quad) ^ sw7) * 8);
#pragma unroll
            for (int qt2 = 0; qt2 < 2; ++qt2) {
                ot[mt][qt2] = __builtin_amdgcn_mfma_f32_16x16x32_bf16(va0, pb[qt2][0], ot[mt][qt2], 0, 0, 0);
                ot[mt][qt2] = __builtin_amdgcn_mfma_f32_16x16x32_bf16(va1, pb[qt2][1], ot[mt][qt2], 0, 0, 0);
            }
        }
#pragma unroll
        for (int qt2 = 0; qt2 < 2; ++qt2) {
            lacc[qt2] = __builtin_amdgcn_mfma_f32_16x16x32_bf16(ones, pb[qt2][0], lacc[qt2], 0, 0, 0);
            lacc[qt2] = __builtin_amdgcn_mfma_f32_16x16x32_bf16(ones, pb[qt2][1], lacc[qt2], 0, 0, 0);
        }
    };

    stage(&Ks[0][0], &Vs[0][0], 0);
#pragma unroll 1
    for (int kt = 0; kt < nkt; kt += 2) {
        __syncthreads();
        stage(&Ks[1][0], &Vs[1][0], kt + 1);
        compute(&Ks[0][0], &Vs[0][0], kt * 64);
        __syncthreads();
        if (kt + 2 < nkt) stage(&Ks[0][0], &Vs[0][0], kt + 2);
        compute(&Ks[1][0], &Vs[1][0], (kt + 1) * 64);
    }

    lds_fence_wave();
#pragma unroll
    for (int qt2 = 0; qt2 < 2; ++qt2) {
        const float il = 1.0f / lacc[qt2][0];
        u16* prow = qt2 ? prow1 : prow0;
#pragma unroll
        for (int mt = 0; mt < 4; ++mt) {
            uint2 ov;
            ov.x = pkbf2(ot[mt][qt2][0] * il, ot[mt][qt2][1] * il);
            ov.y = pkbf2(ot[mt][qt2][2] * il, ot[mt][qt2][3] * il);
            *reinterpret_cast<uint2*>(prow + ((2 * mt + (quad >> 1)) ^ sw7) * 8) = ov;
        }
    }
    lds_fence_wave();
    const int r2 = lane >> 1, half = lane & 1;
    const u16* orow = Pw + r2 * 64;
    u16* gout = A2 + ((size_t)b * S_LEN + q0w + r2) * DMODEL + h * DKH + half * 32;
#pragma unroll
    for (int c = 0; c < 4; ++c) {
        uint4 val = *reinterpret_cast<const uint4*>(orow + (((half * 4 + c) ^ (r2 & 7))) * 8);
        *reinterpret_cast<uint4*>(gout + c * 8) = val;
    }
}

// ---------------- output projection ----------------
__global__ __launch_bounds__(256) void gemm_oproj_kernel(const u16* __restrict__ A2, const u16* __restrict__ Wo,
                                                         float* __restrict__ Cout) {
    __shared__ u16 As[3 * 128 * 32];
    __shared__ u16 Bs[3 * 128 * 32];
    f32x4 acc[4][4];
    const f32x4 zz = {0.f, 0.f, 0.f, 0.f};
#pragma unroll
    for (int i = 0; i < 4; ++i)
#pragma unroll
        for (int j = 0; j < 4; ++j) acc[i][j] = zz;

    const int m0 = blockIdx.y * 128;
    const int n0 = blockIdx.x * 128;
    gemm_core(A2, Wo, DMODEL, m0, n0, As, Bs, acc);

    const int lane = threadIdx.x & 63;
    const int quad = lane >> 4, l15 = lane & 15;
    const int w = threadIdx.x >> 6, mq = w & 1, nq = w >> 1;
#pragma unroll
    for (int nt = 0; nt < 4; ++nt) {
        const int ncol = n0 + nq*64 + nt*16 + l15;
#pragma unroll
        for (int mt = 0; mt < 4; ++mt) {
            const int mrow = m0 + mq*64 + mt*16 + quad*4;
#pragma unroll
            for (int r = 0; r < 4; ++r)
                Cout[(size_t)(mrow + r) * DMODEL + ncol] = acc[mt][nt][r];
        }
    }
}

extern "C" void kernel_launch(void* const* d_in, const int* in_sizes, int n_in,
                              void* d_out, int out_size, void* d_ws, size_t ws_size,
                              hipStream_t stream) {
    const float* x  = (const float*)d_in[0];
    const float* PQ = (const float*)d_in[1];
    const float* PK = (const float*)d_in[2];
    const float* PV = (const float*)d_in[3];
    const float* PO = (const float*)d_in[4];
    float* out = (float*)d_out;
    char* ws = (char*)d_ws;

    const size_t MB = 1u << 20;
    u16* xb   = (u16*)(ws + 0 * MB);
    u16* Wqkv = (u16*)(ws + 16 * MB);
    u16* Wo   = (u16*)(ws + 22 * MB);
    u16* Qb   = (u16*)(ws + 24 * MB);
    u16* Kb   = (u16*)(ws + 40 * MB);
    u16* Vt   = (u16*)(ws + 56 * MB);
    u16* A2   = (u16*)(ws + 72 * MB);

    cvt_all<<<dim3(12288), dim3(256), 0, stream>>>(x, PQ, PK, PV, PO, xb, Wqkv, Wo);

    gemm_qkv_kernel<<<dim3(24, 64), dim3(256), 0, stream>>>(xb, Wqkv, Qb, Kb, Vt);

    attn_kernel<<<dim3(1024), dim3(256), 0, stream>>>(Qb, Kb, Vt, A2);

    gemm_oproj_kernel<<<dim3(8, 64), dim3(256), 0, stream>>>(A2, Wo, out);
}

// Round 7
// 266.014 us; speedup vs baseline: 1.0259x; 1.0259x over previous
//
#include <hip/hip_runtime.h>

typedef unsigned short u16;
typedef unsigned int u32;
typedef float f32x4 __attribute__((ext_vector_type(4)));
typedef __bf16 bf16x8 __attribute__((ext_vector_type(8)));

#define S_LEN 2048
#define DMODEL 1024
#define NHEAD 16
#define DKH 64

__device__ __forceinline__ u16 f2bf(float f) {
    unsigned u = __float_as_uint(f);
    u += 0x7FFFu + ((u >> 16) & 1u);   // RNE
    return (u16)(u >> 16);
}

// packed f32x2 -> bf16x2 (RNE)
__device__ __forceinline__ u32 pkbf2(float a, float b) {
#if __has_builtin(__builtin_amdgcn_cvt_pk_bf16_f32)
    typedef __bf16 bf16x2_t __attribute__((ext_vector_type(2)));
    bf16x2_t r = __builtin_amdgcn_cvt_pk_bf16_f32(a, b);
    u32 u; __builtin_memcpy(&u, &r, 4); return u;
#else
    return (u32)f2bf(a) | ((u32)f2bf(b) << 16);
#endif
}

#if __has_builtin(__builtin_amdgcn_exp2f)
#define EXP2(x) __builtin_amdgcn_exp2f(x)
#else
#define EXP2(x) exp2f(x)
#endif

// wave-level LDS write->read ordering WITHOUT draining vmcnt (keeps glds prefetch alive)
__device__ __forceinline__ void lds_fence_wave() {
    __asm__ volatile("" ::: "memory");
    __builtin_amdgcn_s_waitcnt(0xC07F);   // lgkmcnt(0), vmcnt/expcnt untouched
    __asm__ volatile("" ::: "memory");
}

// async global->LDS, 16B per lane
__device__ __forceinline__ void glds16(const u16* g, u16* l) {
    __builtin_amdgcn_global_load_lds(
        (const __attribute__((address_space(1))) void*)(g),
        (__attribute__((address_space(3))) void*)(l), 16, 0, 0);
}

// ---------------- fused fp32 -> bf16 convert (x + 4 weights in one launch) ----------------
__global__ __launch_bounds__(256) void cvt_all(const float* __restrict__ x, const float* __restrict__ PQ,
                                               const float* __restrict__ PK, const float* __restrict__ PV,
                                               const float* __restrict__ PO,
                                               u16* __restrict__ xb, u16* __restrict__ Wqkv,
                                               u16* __restrict__ Wo) {
    int i = blockIdx.x * 256 + threadIdx.x;
    const float* src; u16* dst; int j;
    if (i < 2097152)      { src = x;  dst = xb;             j = i; }
    else if (i < 2359296) { src = PQ; dst = Wqkv;           j = i - 2097152; }
    else if (i < 2621440) { src = PK; dst = Wqkv + 1048576; j = i - 2359296; }
    else if (i < 2883584) { src = PV; dst = Wqkv + 2097152; j = i - 2621440; }
    else                  { src = PO; dst = Wo;             j = i - 2883584; }
    float4 v = reinterpret_cast<const float4*>(src)[j];
    uint2 o;
    o.x = pkbf2(v.x, v.y);
    o.y = pkbf2(v.z, v.w);
    reinterpret_cast<uint2*>(dst)[j] = o;
}

// ---------------- GEMM core: C = A * Bt^T, 128x128 tile, BK=32 (R5 version) ----------------
// Double-buffered (1 barrier/iter), conflict-free swizzle swiz(row)=(row>>1)&3.
__device__ __forceinline__ void gemm_core(const u16* __restrict__ A, const u16* __restrict__ Bt,
                                          int K, int m0, int n0,
                                          u16* As, u16* Bs, f32x4 acc[4][4]) {
    const int tid  = threadIdx.x;
    const int lane = tid & 63;
    const int quad = lane >> 4, l15 = lane & 15;
    const int w    = tid >> 6;
    const int mq   = w & 1, nq = w >> 1;

    const int c0 = tid, c1 = tid + 256;
    const int r0 = c0 >> 2, k0 = ((c0 & 3) ^ ((r0 >> 1) & 3)) * 8;
    const int r1 = c1 >> 2, k1 = ((c1 & 3) ^ ((r1 >> 1) & 3)) * 8;
    const u16* ga0 = A  + (size_t)(m0 + r0) * K + k0;
    const u16* ga1 = A  + (size_t)(m0 + r1) * K + k1;
    const u16* gb0 = Bt + (size_t)(n0 + r0) * K + k0;
    const u16* gb1 = Bt + (size_t)(n0 + r1) * K + k1;

    const int swz = (quad ^ ((l15 >> 1) & 3)) * 8;

    auto stage = [&](int buf, int kk) {
        u16* ad = As + buf * 4096;
        u16* bd = Bs + buf * 4096;
        glds16(ga0 + kk, ad + c0 * 8);
        glds16(ga1 + kk, ad + c1 * 8);
        glds16(gb0 + kk, bd + c0 * 8);
        glds16(gb1 + kk, bd + c1 * 8);
    };

    stage(0, 0);
    for (int kk = 0; kk < K; kk += 32) {
        const int cur = (kk >> 5) & 1;
        __syncthreads();                       // drains stage(cur); all waves done with other buf
        if (kk + 32 < K) stage(cur ^ 1, kk + 32);   // flies over compute(cur)
        const u16* ra = As + cur * 4096 + (mq * 64 + l15) * 32 + swz;
        const u16* rb = Bs + cur * 4096 + (nq * 64 + l15) * 32 + swz;
        bf16x8 af[4], bfv[4];
#pragma unroll
        for (int t = 0; t < 4; ++t) {
            af[t]  = *reinterpret_cast<const bf16x8*>(ra + t * 512);
            bfv[t] = *reinterpret_cast<const bf16x8*>(rb + t * 512);
        }
#pragma unroll
        for (int mt = 0; mt < 4; ++mt)
#pragma unroll
            for (int nt = 0; nt < 4; ++nt)
                acc[mt][nt] = __builtin_amdgcn_mfma_f32_16x16x32_bf16(af[mt], bfv[nt], acc[mt][nt], 0, 0, 0);
    }
}

// ---------------- QKV projection + RoPE epilogue (Q pre-scaled by 1/8*log2e) ----------------
__global__ __launch_bounds__(256) void gemm_qkv_kernel(const u16* __restrict__ xb, const u16* __restrict__ Wqkv,
                                                       u16* __restrict__ Qb, u16* __restrict__ Kb,
                                                       u16* __restrict__ Vt) {
    __shared__ u16 As[2 * 128 * 32];
    __shared__ u16 Bs[2 * 128 * 32];
    f32x4 acc[4][4];
    const f32x4 zz = {0.f, 0.f, 0.f, 0.f};
#pragma unroll
    for (int i = 0; i < 4; ++i)
#pragma unroll
        for (int j = 0; j < 4; ++j) acc[i][j] = zz;

    const int m0 = blockIdx.y * 128;
    const int n0 = blockIdx.x * 128;
    gemm_core(xb, Wqkv, DMODEL, m0, n0, As, Bs, acc);

    const int lane = threadIdx.x & 63;
    const int quad = lane >> 4, l15 = lane & 15;
    const int w = threadIdx.x >> 6, mq = w & 1, nq = w >> 1;

#pragma unroll
    for (int nt = 0; nt < 4; ++nt) {
        const int ncol = n0 + nq*64 + nt*16 + l15;
        const int sel  = ncol >> 10;         // 0=Q,1=K,2=V (block-uniform)
        const int e    = ncol & 1023;
        const int h    = e >> 6, dk = e & 63;
#pragma unroll
        for (int mt = 0; mt < 4; ++mt) {
            const int mrow = m0 + mq*64 + mt*16 + quad*4;
            if (sel == 2) {
                int b = mrow >> 11, s = mrow & 2047;
                uint2 pv;
                pv.x = pkbf2(acc[mt][nt][0], acc[mt][nt][1]);
                pv.y = pkbf2(acc[mt][nt][2], acc[mt][nt][3]);
                *reinterpret_cast<uint2*>(&Vt[((size_t)(b * NHEAD + h) * DKH + dk) * S_LEN + s]) = pv;
            } else {
                float invf_rev = 0.15915494f * EXP2(-13.2877124f * (float)(dk & 62) * (1.0f / 64.0f));
                const float sc = sel ? 1.0f : 0.18033688f;   // fold softmax scale*log2e into Q
                u16* dst = sel ? Kb : Qb;
#pragma unroll
                for (int r = 0; r < 4; ++r) {
                    float val  = acc[mt][nt][r];
                    float part = __shfl_xor(val, 1);
                    int m = mrow + r;
                    int b = m >> 11, s = m & 2047;
                    float rev = (float)s * invf_rev;
                    float fr  = rev - floorf(rev);
#if __has_builtin(__builtin_amdgcn_sinf) && __has_builtin(__builtin_amdgcn_cosf)
                    float sn = __builtin_amdgcn_sinf(fr);   // sin(2*pi*fr)
                    float cs = __builtin_amdgcn_cosf(fr);
#else
                    float sn, cs;
                    __sincosf(fr * 6.2831853f, &sn, &cs);
#endif
                    sn *= sc; cs *= sc;
                    float o = (dk & 1) ? (part * sn + val * cs)
                                       : (val * cs - part * sn);
                    dst[((size_t)(b * NHEAD + h) * S_LEN + s) * DKH + dk] = f2bf(o);
                }
            }
        }
    }
}

// ---------------- flash attention v3: 64 q per wave (256 q per block) ----------------
// grid 512: block i -> bh = i&63, qblk = (i<256) ? 7-((i>>6)&3) : (i>>6)&3
// (blocks i and i+256 land on the same CU slot -> paired work p + (7-p) = uniform).
// Per iter (64 keys): K/V frags read ONCE per wave and amortized over 64 q.
__global__ __launch_bounds__(256, 2) void attn_kernel(const u16* __restrict__ Qb, const u16* __restrict__ Kb,
                                                      const u16* __restrict__ Vt, u16* __restrict__ A2) {
    __shared__ u16 Ks[2][64 * 64];     // [buf][key][dk-chunk swizzled]
    __shared__ u16 Vs[2][64 * 64];     // [buf][dk][key-chunk swizzled]
    __shared__ u16 Ps[4][64 * 64];     // per-wave P / O buffer (64q x 64k), chunk-swizzled

    const int tid  = threadIdx.x;
    const int lane = tid & 63, w = tid >> 6;
    const int quad = lane >> 4, l15 = lane & 15;
    const int i    = blockIdx.x;
    const int bh   = i & 63;
    const int tq   = (i >> 6) & 3;
    const int qblk = (i < 256) ? (7 - tq) : tq;   // LPT first, pair-complement second
    const int b = bh >> 4, h = bh & 15;
    const int q0w = qblk * 256 + w * 64;
    const int nkt = 4 * (qblk + 1);
    const int sw7 = l15 & 7;
    const f32x4 zz = {0.f, 0.f, 0.f, 0.f};

    uint4 ob; ob.x = ob.y = ob.z = ob.w = 0x3F803F80u;
    bf16x8 ones; __builtin_memcpy(&ones, &ob, 16);

    // Q fragments (B-operand: n=q, k=dk), loop-invariant: 8 x bf16x8
    bf16x8 qf[4][2];
#pragma unroll
    for (int qt = 0; qt < 4; ++qt)
#pragma unroll
        for (int kh = 0; kh < 2; ++kh)
            qf[qt][kh] = *reinterpret_cast<const bf16x8*>(
                Qb + ((size_t)bh * S_LEN + q0w + qt * 16 + l15) * DKH + kh * 32 + quad * 8);

    f32x4 ot[4][4], lacc[4];           // ot[mt=dk][qt], 64 dk x 64 q per wave
#pragma unroll
    for (int mt = 0; mt < 4; ++mt)
#pragma unroll
        for (int qt = 0; qt < 4; ++qt) ot[mt][qt] = zz;
#pragma unroll
    for (int qt = 0; qt < 4; ++qt) lacc[qt] = zz;

    const int c0 = tid, c1 = tid + 256;
    const int r0 = c0 >> 3, kc0 = ((c0 & 7) ^ (r0 & 7)) * 8;
    const int r1 = c1 >> 3, kc1 = ((c1 & 7) ^ (r1 & 7)) * 8;
    const u16* gk0 = Kb + ((size_t)bh * S_LEN + r0) * DKH + kc0;
    const u16* gk1 = Kb + ((size_t)bh * S_LEN + r1) * DKH + kc1;
    const u16* gv0 = Vt + ((size_t)bh * DKH + r0) * S_LEN + kc0;
    const u16* gv1 = Vt + ((size_t)bh * DKH + r1) * S_LEN + kc1;
    u16* Pw = &Ps[w][0];

    auto stage = [&](u16* kdst, u16* vdst, int kt) {
        const size_t key0 = (size_t)kt * 64;
        glds16(gk0 + key0 * DKH, kdst + c0 * 8);
        glds16(gk1 + key0 * DKH, kdst + c1 * 8);
        glds16(gv0 + key0,       vdst + c0 * 8);
        glds16(gv1 + key0,       vdst + c1 * 8);
    };

    auto compute = [&](const u16* Kbuf, const u16* Vbuf, int key0) {
        const bool edge = (key0 + 63 > q0w + 63 - 192 + (3 - w) * 0) && (key0 + 63 > q0w);  // wave-uniform
        // ---- S phase: per key-tile, K frags read once, used by all 4 q-tiles ----
#pragma unroll
        for (int kt4 = 0; kt4 < 4; ++kt4) {
            const u16* krow = Kbuf + (kt4 * 16 + l15) * 64;
            bf16x8 ka0 = *reinterpret_cast<const bf16x8*>(krow + (quad ^ sw7) * 8);
            bf16x8 ka1 = *reinterpret_cast<const bf16x8*>(krow + ((4 + quad) ^ sw7) * 8);
#pragma unroll
            for (int qt = 0; qt < 4; ++qt) {
                f32x4 s = __builtin_amdgcn_mfma_f32_16x16x32_bf16(ka0, qf[qt][0], zz, 0, 0, 0);
                s = __builtin_amdgcn_mfma_f32_16x16x32_bf16(ka1, qf[qt][1], s, 0, 0, 0);
                if (edge) {
                    const int qrow = q0w + qt * 16 + l15;
                    const int kbase = key0 + kt4 * 16 + quad * 4;
#pragma unroll
                    for (int r = 0; r < 4; ++r)
                        if (kbase + r > qrow) s[r] = -3.0e38f;
                }
                uint2 pv;
                pv.x = pkbf2(EXP2(s[0]), EXP2(s[1]));
                pv.y = pkbf2(EXP2(s[2]), EXP2(s[3]));
                *reinterpret_cast<uint2*>(Pw + (qt * 16 + l15) * 64 + (quad & 1) * 4 +
                                          ((2 * kt4 + (quad >> 1)) ^ sw7) * 8) = pv;
            }
        }
        lds_fence_wave();
        // ---- P fragments (B-operand) ----
        bf16x8 pb[4][2];
#pragma unroll
        for (int qt = 0; qt < 4; ++qt)
#pragma unroll
            for (int kh = 0; kh < 2; ++kh)
                pb[qt][kh] = *reinterpret_cast<const bf16x8*>(
                    Pw + (qt * 16 + l15) * 64 + ((kh * 4 + quad) ^ sw7) * 8);
        // ---- row sums ----
#pragma unroll
        for (int qt = 0; qt < 4; ++qt) {
            lacc[qt] = __builtin_amdgcn_mfma_f32_16x16x32_bf16(ones, pb[qt][0], lacc[qt], 0, 0, 0);
            lacc[qt] = __builtin_amdgcn_mfma_f32_16x16x32_bf16(ones, pb[qt][1], lacc[qt], 0, 0, 0);
        }
        // ---- O phase: V frags read once, used by all 4 q-tiles ----
#pragma unroll
        for (int mt = 0; mt < 4; ++mt) {
            const u16* vrow = Vbuf + (mt * 16 + l15) * 64;
            bf16x8 va0 = *reinterpret_cast<const bf16x8*>(vrow + (quad ^ sw7) * 8);
            bf16x8 va1 = *reinterpret_cast<const bf16x8*>(vrow + ((4 + quad) ^ sw7) * 8);
#pragma unroll
            for (int qt = 0; qt < 4; ++qt) {
                ot[mt][qt] = __builtin_amdgcn_mfma_f32_16x16x32_bf16(va0, pb[qt][0], ot[mt][qt], 0, 0, 0);
                ot[mt][qt] = __builtin_amdgcn_mfma_f32_16x16x32_bf16(va1, pb[qt][1], ot[mt][qt], 0, 0, 0);
            }
        }
    };

    stage(&Ks[0][0], &Vs[0][0], 0);
#pragma unroll 1
    for (int kt = 0; kt < nkt; kt += 2) {
        __syncthreads();
        stage(&Ks[1][0], &Vs[1][0], kt + 1);
        if (kt * 64 <= q0w + 63) compute(&Ks[0][0], &Vs[0][0], kt * 64);       // skip fully-masked
        __syncthreads();
        if (kt + 2 < nkt) stage(&Ks[0][0], &Vs[0][0], kt + 2);
        if ((kt + 1) * 64 <= q0w + 63) compute(&Ks[1][0], &Vs[1][0], (kt + 1) * 64);
    }

    // epilogue: O/l, LDS transpose O^T -> [q][dk], coalesced store
    lds_fence_wave();
#pragma unroll
    for (int qt = 0; qt < 4; ++qt) {
        const float il = 1.0f / lacc[qt][0];
        u16* prow = Pw + (qt * 16 + l15) * 64 + (quad & 1) * 4;
#pragma unroll
        for (int mt = 0; mt < 4; ++mt) {
            uint2 ov;
            ov.x = pkbf2(ot[mt][qt][0] * il, ot[mt][qt][1] * il);
            ov.y = pkbf2(ot[mt][qt][2] * il, ot[mt][qt][3] * il);
            *reinterpret_cast<uint2*>(prow + ((2 * mt + (quad >> 1)) ^ sw7) * 8) = ov;
        }
    }
    lds_fence_wave();
    const int half = lane & 1;
#pragma unroll
    for (int rr = 0; rr < 2; ++rr) {
        const int r2 = rr * 32 + (lane >> 1);
        const u16* orow = Pw + r2 * 64;
        u16* gout = A2 + ((size_t)b * S_LEN + q0w + r2) * DMODEL + h * DKH + half * 32;
#pragma unroll
        for (int c = 0; c < 4; ++c) {
            uint4 val = *reinterpret_cast<const uint4*>(orow + (((half * 4 + c) ^ (r2 & 7))) * 8);
            *reinterpret_cast<uint4*>(gout + c * 8) = val;
        }
    }
}

// ---------------- output projection ----------------
__global__ __launch_bounds__(256) void gemm_oproj_kernel(const u16* __restrict__ A2, const u16* __restrict__ Wo,
                                                         float* __restrict__ Cout) {
    __shared__ u16 As[2 * 128 * 32];
    __shared__ u16 Bs[2 * 128 * 32];
    f32x4 acc[4][4];
    const f32x4 zz = {0.f, 0.f, 0.f, 0.f};
#pragma unroll
    for (int i = 0; i < 4; ++i)
#pragma unroll
        for (int j = 0; j < 4; ++j) acc[i][j] = zz;

    const int m0 = blockIdx.y * 128;
    const int n0 = blockIdx.x * 128;
    gemm_core(A2, Wo, DMODEL, m0, n0, As, Bs, acc);

    const int lane = threadIdx.x & 63;
    const int quad = lane >> 4, l15 = lane & 15;
    const int w = threadIdx.x >> 6, mq = w & 1, nq = w >> 1;
#pragma unroll
    for (int nt = 0; nt < 4; ++nt) {
        const int ncol = n0 + nq*64 + nt*16 + l15;
#pragma unroll
        for (int mt = 0; mt < 4; ++mt) {
            const int mrow = m0 + mq*64 + mt*16 + quad*4;
#pragma unroll
            for (int r = 0; r < 4; ++r)
                Cout[(size_t)(mrow + r) * DMODEL + ncol] = acc[mt][nt][r];
        }
    }
}

extern "C" void kernel_launch(void* const* d_in, const int* in_sizes, int n_in,
                              void* d_out, int out_size, void* d_ws, size_t ws_size,
                              hipStream_t stream) {
    const float* x  = (const float*)d_in[0];
    const float* PQ = (const float*)d_in[1];
    const float* PK = (const float*)d_in[2];
    const float* PV = (const float*)d_in[3];
    const float* PO = (const float*)d_in[4];
    float* out = (float*)d_out;
    char* ws = (char*)d_ws;

    const size_t MB = 1u << 20;
    u16* xb   = (u16*)(ws + 0 * MB);
    u16* Wqkv = (u16*)(ws + 16 * MB);
    u16* Wo   = (u16*)(ws + 22 * MB);
    u16* Qb   = (u16*)(ws + 24 * MB);
    u16* Kb   = (u16*)(ws + 40 * MB);
    u16* Vt   = (u16*)(ws + 56 * MB);
    u16* A2   = (u16*)(ws + 72 * MB);

    cvt_all<<<dim3(12288), dim3(256), 0, stream>>>(x, PQ, PK, PV, PO, xb, Wqkv, Wo);

    gemm_qkv_kernel<<<dim3(24, 64), dim3(256), 0, stream>>>(xb, Wqkv, Qb, Kb, Vt);

    // 64q-per-wave flash attention: 512 blocks (64 bh x 8 q-blocks, pair-mapped)
    attn_kernel<<<dim3(512), dim3(256), 0, stream>>>(Qb, Kb, Vt, A2);

    gemm_oproj_kernel<<<dim3(8, 64), dim3(256), 0, stream>>>(A2, Wo, out);
}